// Round 4
// baseline (270.472 us; speedup 1.0000x reference)
//
#include <hip/hip_runtime.h>

// DerivativeNet direction='x': B=16,C=2,H=1024,W=1024 fp32.
// Persistent-block pipeline: 2048 blocks (8/CU), each processes 8 consecutive
// rows with a 1-deep software prefetch (row t+1's 3 float4 loads in flight
// while row t computes). Per-row barrier is lgkmcnt-only (inline asm +
// raw s_barrier) so prefetch loads stay in flight across it (T3/T4 pattern).
// Mask logic: ballot + 64-bit scalar mask algebra + mbcnt (no scan chains).
// Cross-wave glue: parity-double-buffered 56B LDS, one barrier per row.

typedef float v4f __attribute__((ext_vector_type(4)));

__device__ __forceinline__ int prefix_below(unsigned long long m) {
    // popcount of m over lanes strictly below this lane
    return (int)__builtin_amdgcn_mbcnt_hi(
        (unsigned)(m >> 32),
        __builtin_amdgcn_mbcnt_lo((unsigned)(m & 0xffffffffull), 0u));
}

#define ROWS 8

__global__ __launch_bounds__(256, 8) void deriv_x_kernel(
    const float* __restrict__ u,
    const float* __restrict__ mask,
    float* __restrict__ out)
{
    const int tid  = threadIdx.x;        // owns elements 4tid..4tid+3 of each row
    const int lane = tid & 63;
    const int wave = tid >> 6;
    const int row0 = blockIdx.x * ROWS;  // 8 consecutive rows, same batch b
    const int b    = row0 >> 10;
    const int y0   = row0 & 1023;

    // float4-granularity pointers; +256 float4s per row
    const float4* mp  = (const float4*)mask + ((size_t)row0 << 8) + tid;
    const float4* u0p = (const float4*)u + ((size_t)b << 19) + ((size_t)y0 << 8) + tid;
    const float4* u1p = u0p + (size_t)(1 << 18);   // channel 1 is 1M floats away
    v4f* o0p = (v4f*)out + ((size_t)b << 19) + ((size_t)y0 << 8) + tid;
    v4f* o1p = o0p + (size_t)(1 << 18);

    // cross-wave glue, parity-double-buffered
    __shared__ int   s_tot[2][4];
    __shared__ int   s_b3[2][4], s_b0[2][4];
    __shared__ float s_last0[2][4], s_last1[2][4];
    __shared__ float s_first0[2][4], s_first1[2][4];

    // prologue: row 0 in flight
    float4 m4 = mp[0];
    float4 a4 = u0p[0];
    float4 c4 = u1p[0];

    const float inv2h = 50.0f;    // 1/(2h), h=0.01
    const float invh  = 100.0f;   // 1/h

    #pragma unroll
    for (int r = 0; r < ROWS; ++r) {
        const int p = r & 1;

        // ---- issue next row's loads FIRST (stay in flight through the barrier)
        float4 m4n, a4n, c4n;
        if (r + 1 < ROWS) {
            m4n = mp [(size_t)(r + 1) << 8];
            a4n = u0p[(size_t)(r + 1) << 8];
            c4n = u1p[(size_t)(r + 1) << 8];
        }

        // ---- ballots for current row (uniform 64-bit masks)
        const int i0 = (m4.x != 0.f), i1 = (m4.y != 0.f);
        const int i2 = (m4.z != 0.f), i3 = (m4.w != 0.f);
        const unsigned long long B0 = __ballot(i0);
        const unsigned long long B1 = __ballot(i1);
        const unsigned long long B2 = __ballot(i2);
        const unsigned long long B3 = __ballot(i3);
        const int wtot = __popcll(B0) + __popcll(B1) + __popcll(B2) + __popcll(B3);

        if (lane == 0) {
            s_tot[p][wave]    = wtot;
            s_b3[p][wave]     = (int)(B3 >> 63);
            s_b0[p][wave]     = (int)(B0 & 1ull);
            s_first0[p][wave] = a4.x;
            s_first1[p][wave] = c4.x;
        }
        if (lane == 63) {
            s_last0[p][wave] = a4.w;
            s_last1[p][wave] = c4.w;
        }

        // lgkmcnt-only barrier: glue writes visible, prefetch vmcnt NOT drained
        asm volatile("s_waitcnt lgkmcnt(0)" ::: "memory");
        __builtin_amdgcn_s_barrier();

        const int t0 = s_tot[p][0], t1 = s_tot[p][1], t2 = s_tot[p][2], t3 = s_tot[p][3];
        const int total = t0 + t1 + t2 + t3;
        int base = 0;
        if (wave > 0) base += t0;
        if (wave > 1) base += t1;
        if (wave > 2) base += t2;

        const int lcbit = (wave > 0) ? s_b3[p][wave - 1] : 0;
        const int rcbit = (wave < 3) ? s_b0[p][wave + 1] : 0;
        const float ulb0 = (wave > 0) ? s_last0[p][wave - 1] : 0.f;
        const float ulb1 = (wave > 0) ? s_last1[p][wave - 1] : 0.f;
        const float urb0 = (wave < 3) ? s_first0[p][wave + 1] : 0.f;
        const float urb1 = (wave < 3) ? s_first1[p][wave + 1] : 0.f;

        // eroded 3-box via 64-bit mask algebra
        const unsigned long long L0 = (B3 << 1) | (unsigned long long)lcbit;
        const unsigned long long R3 = (B0 >> 1) | ((unsigned long long)rcbit << 63);
        const unsigned long long E0 = L0 & B0 & B1;
        const unsigned long long E1 = B0 & B1 & B2;
        const unsigned long long E2 = B1 & B2 & B3;
        const unsigned long long E3 = B2 & B3 & R3;

        const float er0 = ((E0 >> lane) & 1ull) ? 1.f : 0.f;
        const float er1 = ((E1 >> lane) & 1ull) ? 1.f : 0.f;
        const float er2 = ((E2 >> lane) & 1ull) ? 1.f : 0.f;
        const float er3 = ((E3 >> lane) & 1ull) ? 1.f : 0.f;

        // inclusive cumsum at the 4 owned elements (exact integer)
        const int excl = base + prefix_below(B0) + prefix_below(B1) +
                                prefix_below(B2) + prefix_below(B3);
        const int cs0 = excl + i0;
        const int cs1 = cs0 + i1;
        const int cs2 = cs1 + i2;
        const int cs3 = cs2 + i3;

        const float e10 = (cs0 == 1) ? 1.f : 0.f;
        const float e11 = (cs1 == 1) ? 1.f : 0.f;
        const float e12 = (cs2 == 1) ? 1.f : 0.f;
        const float e13 = (cs3 == 1) ? 1.f : 0.f;
        const float e20 = (i0 && cs0 == total) ? 1.f : 0.f;
        const float e21 = (i1 && cs1 == total) ? 1.f : 0.f;
        const float e22 = (i2 && cs2 == total) ? 1.f : 0.f;
        const float e23 = (i3 && cs3 == total) ? 1.f : 0.f;

#define DO_CH(V, ULB, URB, OPP)                                                    \
        {                                                                          \
            float ul = __shfl_up(V.w, 1);                                          \
            if (lane == 0) ul = ULB;                                               \
            float ur = __shfl_down(V.x, 1);                                        \
            if (lane == 63) ur = URB;                                              \
            v4f o;                                                                 \
            o.x = er0*((V.y - ul )*inv2h) + e10*((V.y - V.x)*invh) + e20*((V.x - ul )*invh); \
            o.y = er1*((V.z - V.x)*inv2h) + e11*((V.z - V.y)*invh) + e21*((V.y - V.x)*invh); \
            o.z = er2*((V.w - V.y)*inv2h) + e12*((V.w - V.z)*invh) + e22*((V.z - V.y)*invh); \
            o.w = er3*((ur  - V.z)*inv2h) + e13*((ur  - V.w)*invh) + e23*((V.w - V.z)*invh); \
            OPP[(size_t)r << 8] = o;                                               \
        }

        DO_CH(a4, ulb0, urb0, o0p)
        DO_CH(c4, ulb1, urb1, o1p)
#undef DO_CH

        // rotate pipeline registers
        m4 = m4n; a4 = a4n; c4 = c4n;
    }
}

extern "C" void kernel_launch(void* const* d_in, const int* in_sizes, int n_in,
                              void* d_out, int out_size, void* d_ws, size_t ws_size,
                              hipStream_t stream) {
    const float* u    = (const float*)d_in[0];
    const float* mask = (const float*)d_in[1];
    float* out        = (float*)d_out;
    // 16384 rows / 8 rows per block = 2048 blocks = 8 per CU
    deriv_x_kernel<<<dim3(2048), dim3(256), 0, stream>>>(u, mask, out);
}

// Round 5
// 265.018 us; speedup vs baseline: 1.0206x; 1.0206x over previous
//
#include <hip/hip_runtime.h>

// DerivativeNet direction='x': B=16,C=2,H=1024,W=1024 fp32.
// One block (256 thr = 4 waves) per row; ballot/mbcnt mask algebra.
// Barrier decoupled: LDS carries ONLY the 4 per-wave mask counts (16 B),
// synced with an lgkmcnt-only barrier (u loads stay in flight across it).
// Wave-boundary halos (mask,u0,u1) come from 2-lane global loads (L2 hits),
// not LDS, so no vmcnt drain is ever required before the barrier.

typedef float v4f __attribute__((ext_vector_type(4)));

__device__ __forceinline__ int prefix_below(unsigned long long m) {
    // popcount of m over lanes strictly below this lane
    return (int)__builtin_amdgcn_mbcnt_hi(
        (unsigned)(m >> 32),
        __builtin_amdgcn_mbcnt_lo((unsigned)(m & 0xffffffffull), 0u));
}

__global__ __launch_bounds__(256) void deriv_x_kernel(
    const float* __restrict__ u,
    const float* __restrict__ mask,
    float* __restrict__ out)
{
    const int tid  = threadIdx.x;        // owns elements 4tid..4tid+3
    const int lane = tid & 63;
    const int wave = tid >> 6;
    const int row  = blockIdx.x;         // b*1024 + y
    const int b    = row >> 10;
    const int y    = row & 1023;

    const size_t moff  = (size_t)row << 10;                     // mask[b,0,y,:]
    const size_t u0off = ((size_t)b << 21) + ((size_t)y << 10); // u[b,0,y,:]
    const size_t u1off = u0off + (size_t)(1 << 20);             // u[b,1,y,:]

    // ---- main loads: mask FIRST (it alone gates the barrier path)
    const float4 m4 = ((const float4*)(mask + moff))[tid];
    const float4 a4 = ((const float4*)(u + u0off))[tid];
    const float4 c4 = ((const float4*)(u + u1off))[tid];

    // ---- wave-boundary halo loads (2 active lanes/wave, L2-resident lines)
    float blm = 0.f, bl0 = 0.f, bl1 = 0.f;   // element left of wave span
    float brm = 0.f, br0 = 0.f, br1 = 0.f;   // element right of wave span
    if (lane == 0 && wave > 0) {
        const int e = (wave << 8) - 1;
        blm = mask[moff + e];
        bl0 = u[u0off + e];
        bl1 = u[u1off + e];
    }
    if (lane == 63 && wave < 3) {
        const int e = (wave << 8) + 256;
        brm = mask[moff + e];
        br0 = u[u0off + e];
        br1 = u[u1off + e];
    }

    // ---- ballots (uniform 64-bit masks in SGPRs) — waits only on m4
    const int i0 = (m4.x != 0.f), i1 = (m4.y != 0.f);
    const int i2 = (m4.z != 0.f), i3 = (m4.w != 0.f);
    const unsigned long long B0 = __ballot(i0);
    const unsigned long long B1 = __ballot(i1);
    const unsigned long long B2 = __ballot(i2);
    const unsigned long long B3 = __ballot(i3);
    const int wtot = __popcll(B0) + __popcll(B1) + __popcll(B2) + __popcll(B3);

    // ---- cross-wave glue: ONLY the 4 wave counts (16 B of LDS)
    __shared__ int s_tot[4];
    if (lane == 0) s_tot[wave] = wtot;

    // lgkmcnt-only barrier: ds_write visible, u loads NOT drained
    asm volatile("s_waitcnt lgkmcnt(0)" ::: "memory");
    __builtin_amdgcn_s_barrier();
    asm volatile("" ::: "memory");       // compiler fence: no LDS-read hoisting

    const int t0 = s_tot[0], t1 = s_tot[1], t2 = s_tot[2], t3 = s_tot[3];
    const int total = t0 + t1 + t2 + t3;
    int base = 0;
    if (wave > 0) base += t0;
    if (wave > 1) base += t1;
    if (wave > 2) base += t2;

    // ---- eroded 3-box via 64-bit mask algebra (wave-interior)
    const unsigned long long L0 = (B3 << 1);   // lane0 fixed up below
    const unsigned long long R3 = (B0 >> 1);   // lane63 fixed up below
    const unsigned long long E0 = L0 & B0 & B1;
    const unsigned long long E1 = B0 & B1 & B2;
    const unsigned long long E2 = B1 & B2 & B3;
    const unsigned long long E3 = B2 & B3 & R3;

    float er0 = ((E0 >> lane) & 1ull) ? 1.f : 0.f;
    const float er1 = ((E1 >> lane) & 1ull) ? 1.f : 0.f;
    const float er2 = ((E2 >> lane) & 1ull) ? 1.f : 0.f;
    float er3 = ((E3 >> lane) & 1ull) ? 1.f : 0.f;
    // boundary-lane overrides from halo loads (zero-pad handled by blm/brm=0)
    if (lane == 0)  er0 = (blm != 0.f && i0 && i1) ? 1.f : 0.f;
    if (lane == 63) er3 = (i2 && i3 && brm != 0.f) ? 1.f : 0.f;

    // ---- inclusive cumsum at the 4 owned elements (exact integer)
    const int excl = base + prefix_below(B0) + prefix_below(B1) +
                            prefix_below(B2) + prefix_below(B3);
    const int cs0 = excl + i0;
    const int cs1 = cs0 + i1;
    const int cs2 = cs1 + i2;
    const int cs3 = cs2 + i3;

    const float e10 = (cs0 == 1) ? 1.f : 0.f;
    const float e11 = (cs1 == 1) ? 1.f : 0.f;
    const float e12 = (cs2 == 1) ? 1.f : 0.f;
    const float e13 = (cs3 == 1) ? 1.f : 0.f;
    const float e20 = (i0 && cs0 == total) ? 1.f : 0.f;
    const float e21 = (i1 && cs1 == total) ? 1.f : 0.f;
    const float e22 = (i2 && cs2 == total) ? 1.f : 0.f;
    const float e23 = (i3 && cs3 == total) ? 1.f : 0.f;

    const float inv2h = 50.0f;    // 1/(2h), h=0.01
    const float invh  = 100.0f;   // 1/h

#define DO_CH(V, BL, BR, OFF)                                                      \
    {                                                                              \
        float ul = __shfl_up(V.w, 1);                                              \
        if (lane == 0) ul = BL;    /* wave0: BL=0 == zero-pad */                   \
        float ur = __shfl_down(V.x, 1);                                            \
        if (lane == 63) ur = BR;   /* wave3: BR=0 == zero-pad */                   \
        v4f o;                                                                     \
        o.x = er0*((V.y - ul )*inv2h) + e10*((V.y - V.x)*invh) + e20*((V.x - ul )*invh); \
        o.y = er1*((V.z - V.x)*inv2h) + e11*((V.z - V.y)*invh) + e21*((V.y - V.x)*invh); \
        o.z = er2*((V.w - V.y)*inv2h) + e12*((V.w - V.z)*invh) + e22*((V.z - V.y)*invh); \
        o.w = er3*((ur  - V.z)*inv2h) + e13*((ur  - V.w)*invh) + e23*((V.w - V.z)*invh); \
        ((v4f*)(out + OFF))[tid] = o;                                              \
    }

    DO_CH(a4, bl0, br0, u0off)
    DO_CH(c4, bl1, br1, u1off)
#undef DO_CH
}

extern "C" void kernel_launch(void* const* d_in, const int* in_sizes, int n_in,
                              void* d_out, int out_size, void* d_ws, size_t ws_size,
                              hipStream_t stream) {
    const float* u    = (const float*)d_in[0];
    const float* mask = (const float*)d_in[1];
    float* out        = (float*)d_out;
    // one block per (b,y) row: 16*1024 blocks, 256 threads each
    deriv_x_kernel<<<dim3(16 * 1024), dim3(256), 0, stream>>>(u, mask, out);
}